// Round 16
// baseline (164.018 us; speedup 1.0000x reference)
//
#include <hip/hip_runtime.h>
#include <math.h>

#define NCLS 21
#define NCO 20
#define SUB 8                  // sub-blocks per class in sortmask kernel
#define TPB 256
#define RCAP 2048
#define RMAX 2000
#define LDSW 7680              // u64 capacity of resolve's mask LDS (60 KB): nv<=960
#define SCORE_THRESH 0.05f

typedef unsigned long long u64;
typedef unsigned int u32;
typedef unsigned short u16;

// Exact equivalent of (f32_div(inter,uni) > 0.3f):  inter > IOU_MID * uni in f64.
// 0.3f = 10066330*2^-25; midpoint to next float = 20132661*2^-26. RN tie at the
// midpoint rounds to even (0.3f) -> false, matching strict ">". 25b x 24b exact in f64.
#define IOU_MID (20132661.0 / 67108864.0)

__device__ __forceinline__ u64 readlane64(u64 v, int l) {
    u32 lo = (u32)__builtin_amdgcn_readlane((int)(u32)v, l);
    u32 hi = (u32)__builtin_amdgcn_readlane((int)(u32)(v >> 32), l);
    return ((u64)hi << 32) | lo;
}
__device__ __forceinline__ float readlanef(float v, int l) {
    return __uint_as_float((u32)__builtin_amdgcn_readlane((int)__float_as_uint(v), l));
}
__device__ __forceinline__ u64 shflxor64(u64 v, int m) {
    u32 lo = (u32)__shfl_xor((int)(u32)v, m, 64);
    u32 hi = (u32)__shfl_xor((int)(u32)(v >> 32), m, 64);
    return ((u64)hi << 32) | lo;
}

// Compact upper-triangle mask layout, per class:
// chunk ic (64 rows) starts at coff(ic); row (ic<<6)+il has W=nw-ic words
// (words v=ic..nw-1) at coff(ic) + il*W + (v-ic). Total = coff(nw) words.
__device__ __forceinline__ int coff(int ic, int nw) {
    return ((ic * nw - ((ic * (ic - 1)) >> 1)) << 6);
}

// Reference-exact box decode (absmax 0.0 through R1-R15).
__device__ __forceinline__ void decode_box(
    const float* __restrict__ rois, const float* __restrict__ loc,
    int r, int cls, float sh, float sw,
    float& by1, float& bx1, float& by2, float& bx2)
{
    float4 rb = *(const float4*)(rois + r * 4);
    float y1 = rb.x, x1 = rb.y, y2 = rb.z, x2 = rb.w;
    float h = y2 - y1, w = x2 - x1;
    float cy = y1 + 0.5f * h, cx = x1 + 0.5f * w;
    float4 l4 = *(const float4*)(loc + r * (NCLS * 4) + cls * 4);
    float dy = l4.x * 0.1f, dx = l4.y * 0.1f;
    float dh = l4.z * 0.2f, dw = l4.w * 0.2f;
    float ncy = dy * h + cy, ncx = dx * w + cx;
    float nh = expf(dh) * h, nw = expf(dw) * w;
    by1 = fminf(fmaxf(ncy - 0.5f * nh, 0.f), sh);
    bx1 = fminf(fmaxf(ncx - 0.5f * nw, 0.f), sw);
    by2 = fminf(fmaxf(ncy + 0.5f * nh, 0.f), sh);
    bx2 = fminf(fmaxf(ncx + 0.5f * nw, 0.f), sw);
}

// Reference-exact softmax prob (vectorized loads; float op ORDER k=0..20 kept
// identical to prior rounds: max then exp-sum in index order).
__device__ __forceinline__ float softmax_p(
    const float* __restrict__ scores, int r, int cls)
{
    const float* srow = scores + r * NCLS;
    float s[NCLS];
    float4 a0 = *(const float4*)(srow);
    float4 a1 = *(const float4*)(srow + 4);
    float4 a2 = *(const float4*)(srow + 8);
    float4 a3 = *(const float4*)(srow + 12);
    float4 a4 = *(const float4*)(srow + 16);
    s[0]=a0.x; s[1]=a0.y; s[2]=a0.z; s[3]=a0.w;
    s[4]=a1.x; s[5]=a1.y; s[6]=a1.z; s[7]=a1.w;
    s[8]=a2.x; s[9]=a2.y; s[10]=a2.z; s[11]=a2.w;
    s[12]=a3.x; s[13]=a3.y; s[14]=a3.z; s[15]=a3.w;
    s[16]=a4.x; s[17]=a4.y; s[18]=a4.z; s[19]=a4.w;
    s[20]=srow[20];
    float m = -INFINITY;
#pragma unroll
    for (int k = 0; k < NCLS; ++k) m = fmaxf(m, s[k]);
    float sum = 0.f, ec = 0.f;
#pragma unroll
    for (int k = 0; k < NCLS; ++k) {
        float e = expf(s[k] - m);
        sum += e;
        if (k == cls) ec = e;
    }
    return ec / sum;
}

// ---------------------------------------------------------------------------
// K1 sortmask: 160 blocks x 256 (8 sub-blocks per class). Each block
// REDUNDANTLY computes softmax + compaction + rank for its class (cheap: nv
// ~500 keys, LDS same-address broadcast rank — R11's fusion failed because it
// put mask on 20 CUs; this keeps mask at 160 blocks and makes sort redundant
// instead). Sub-block 0 writes ord/nvv; every block computes its 1/8 share of
// the COMPACT mask from its own LDS-sorted boxes. Rank is value-determined,
// so per-block compaction order is irrelevant (deterministic result).
// ---------------------------------------------------------------------------
__global__ __launch_bounds__(TPB) void sortmask_kernel(
    const float* __restrict__ loc, const float* __restrict__ scores,
    const float* __restrict__ rois, const int* __restrict__ ph,
    const int* __restrict__ pw, u64* __restrict__ ord,
    int* __restrict__ nvv, u64* __restrict__ M, int R)
{
    __shared__ u64 vkey[RCAP];         // 16 KB
    __shared__ float4 pb[RCAP];        // 32 KB
    __shared__ float ar[RCAP];         // 8 KB
    __shared__ int cnt;
    const int t = threadIdx.x;
    const int c = blockIdx.x >> 3;     // class-1 index 0..19
    const int s = blockIdx.x & 7;
    const float sh = (float)(*ph), sw = (float)(*pw);
    if (t == 0) cnt = 0;
    __syncthreads();

    // Phase A: softmax + valid-only compaction (unordered).
    for (int r = t; r < R; r += TPB) {
        float p = softmax_p(scores, r, c + 1);
        if (p > SCORE_THRESH) {
            int j = atomicAdd(&cnt, 1);
            vkey[j] = ((u64)(~__float_as_uint(p)) << 32) | (u32)r;
        }
    }
    __syncthreads();
    const int nv = cnt;
    const int nw = (nv + 63) >> 6;
    if (s == 0 && t == 0) nvv[c] = nv;

    // Phase B: rank via LDS same-address broadcast (no readlane — R8 hazard
    // N/A). Read phase into registers, sync, scatter sorted in-place.
    u64 kjs[8]; int rks[8]; int nb = 0;
    for (int ibase = 0; ibase < nv; ibase += TPB) {
        int i = ibase + t;
        u64 kj = 0; int rank = -1;
        if (i < nv) {
            kj = vkey[i];
            rank = 0;
#pragma unroll 4
            for (int j = 0; j < nv; ++j)
                rank += (vkey[j] < kj);
        }
        kjs[nb] = kj; rks[nb] = rank; ++nb;
    }
    __syncthreads();                   // all ranking reads done
    for (int b = 0; b < nb; ++b)
        if (rks[b] >= 0) {
            vkey[rks[b]] = kjs[b];
            if (s == 0) ord[((size_t)c << 11) + rks[b]] = kjs[b];
        }
    __syncthreads();

    // Phase C: decode sorted boxes to LDS.
    for (int i = t; i < nv; i += TPB) {
        int r = (int)(u32)vkey[i];
        float a0, a1, a2, a3;
        decode_box(rois, loc, r, c + 1, sh, sw, a0, a1, a2, a3);
        pb[i] = make_float4(a0, a1, a2, a3);
        ar[i] = (a2 - a0) * (a3 - a1);
    }
    __syncthreads();

    // Phase D: this block's 1/8 share of the mask (R15-verbatim body).
    const int lane = t & 63;
    const int wid = (s << 2) | (t >> 6);     // 0..31 waves per class
    const int ntasks = nw * (nw + 1) / 2;
    u64* Mc = M + ((size_t)c << 16);
    for (int task = wid; task < ntasks; task += SUB * 4) {
        int ic = 0, rm = task;
        while (rm >= nw - ic) { rm -= nw - ic; ++ic; }  // uniform, <=32 iters
        int v = ic + rm;
        int i = (ic << 6) + lane;
        float4 a = pb[i];                    // garbage if i>=nv (not stored)
        float iarea = ar[i];
        float4 rj = pb[(v << 6) + lane];     // loads executed by all lanes
        float ja_l = ar[(v << 6) + lane];
        int jcnt = min(64, nv - (v << 6));
        u64 m = 0;
        for (int jj = 0; jj < jcnt; ++jj) {
            float jy1 = readlanef(rj.x, jj);
            float jx1 = readlanef(rj.y, jj);
            float jy2 = readlanef(rj.z, jj);
            float jx2 = readlanef(rj.w, jj);
            float ja  = readlanef(ja_l, jj);
            float ty1 = fmaxf(a.x, jy1);
            float tx1 = fmaxf(a.y, jx1);
            float ty2 = fminf(a.z, jy2);
            float tx2 = fminf(a.w, jx2);
            float inter = fmaxf(ty2 - ty1, 0.f) * fmaxf(tx2 - tx1, 0.f);
            float uni = fmaxf(iarea + ja - inter, 1e-10f);
            if ((double)inter > IOU_MID * (double)uni) m |= 1ull << jj;
        }
        if (v == ic) m &= (lane < 63) ? (~0ull << (lane + 1)) : 0ull;
        int W = nw - ic;
        if (i < nv) Mc[coff(ic, nw) + lane * W + (v - ic)] = m;
    }
}

// ---------------------------------------------------------------------------
// K2 resolve (R15-verbatim): 20 blocks x 256. LDS-stage compact mask; word
// Gauss-Seidel with in-word ballot fixpoint; emit compact kept list.
// ---------------------------------------------------------------------------
__global__ __launch_bounds__(TPB) void resolve_kernel(
    const u64* __restrict__ ord, const int* __restrict__ nvv,
    const u64* __restrict__ M, u64* __restrict__ kept,
    int* __restrict__ kcnt, int R)
{
    __shared__ u64 mlds[LDSW];         // 60 KB compact mask
    __shared__ u64 keptw[32];
    __shared__ int kc;
    const int t = threadIdx.x;
    const int c = blockIdx.x;
    const int nv = nvv[c];
    const int nw = (nv + 63) >> 6;
    const u64* Mc = M + ((size_t)c << 16);
    const int S = coff(nw, nw);
    const bool lds_ok = (S <= LDSW);
    if (t == 0) kc = 0;
    if (t < 32) keptw[t] = 0;

    if (lds_ok) {
        for (int base = 0; base < S; base += 2048) {
            u64 v[8];
#pragma unroll
            for (int j = 0; j < 8; ++j) {      // 8 independent coalesced loads
                int k = base + (j << 8) + t;
                v[j] = (k < S) ? Mc[k] : 0ull;
            }
#pragma unroll
            for (int j = 0; j < 8; ++j) {
                int k = base + (j << 8) + t;
                if (k < S) mlds[k] = v[j];
            }
        }
    }
    __syncthreads();

#define MLD(idx) (lds_ok ? mlds[(idx)] : Mc[(idx)])
    if (t < 64) {
        const int lane = t;
        u64 remreg = 0;                     // lane l owns removed-word l
        for (int w = 0; w < nw; ++w) {
            const int W = nw - w;
            const int cb = coff(w, nw);
            int i = (w << 6) + lane;
            u64 cw = (i < nv) ? MLD(cb + lane * W) : 0ull;   // diagonal word
            int remn = nv - (w << 6);
            u64 vb = (remn >= 64) ? ~0ull : ((1ull << remn) - 1ull);
            u64 cand = vb & ~readlane64(remreg, w);
            u64 X = cand;
            if (X) {
                for (int it = 0; it < 64; ++it) {
                    u64 contrib = ((X >> lane) & 1ull) ? cw : 0ull;
#pragma unroll
                    for (int d = 1; d < 64; d <<= 1)
                        contrib |= shflxor64(contrib, d);
                    bool keep = ((cand >> lane) & 1ull) &&
                                !((contrib >> lane) & 1ull);
                    u64 Xn = __ballot(keep);
                    if (Xn == X) break;
                    X = Xn;
                }
                if (lane == 0) keptw[w] = X;
                bool lact = (lane > w) && (lane < nw);
                u64 km = X, acc = 0;
                while (km) {                 // wave-uniform ffs (X uniform)
                    int il = __ffsll(km) - 1;
                    km &= km - 1;
                    if (lact) acc |= MLD(cb + il * W + (lane - w));
                }
                if (lact) remreg |= acc;
            }
        }
    }
#undef MLD
    __syncthreads();

    // Compact kept list: (p_bits << 32) | r. Order irrelevant (distinct rows).
    for (int i = t; i < nv; i += TPB) {
        if ((keptw[i >> 6] >> (i & 63)) & 1ull) {
            u64 key = ord[((size_t)c << 11) + i];
            u32 pbits = ~(u32)(key >> 32);
            int k = atomicAdd(&kc, 1);
            kept[((size_t)c << 11) + k] = ((u64)pbits << 32) | (u32)key;
        }
    }
    __syncthreads();
    if (t == 0) kcnt[c] = kc;
}

// ---------------------------------------------------------------------------
// K3 output: 160 blocks x 256 (R11/R13-R15-proven). Block (c, s) owns a row
// range of class c: zero its slice, barrier (drains stores), scatter in-range
// kept rows (decode recompute + stored prob bits).
// ---------------------------------------------------------------------------
__global__ __launch_bounds__(TPB) void output_kernel(
    const float* __restrict__ loc, const float* __restrict__ rois,
    const int* __restrict__ ph, const int* __restrict__ pw,
    const u64* __restrict__ kept, const int* __restrict__ kcnt,
    float* __restrict__ out, int R)
{
    const int t = threadIdx.x;
    const int c = blockIdx.x >> 3;
    const int s = blockIdx.x & 7;
    const int chunk = (R + 7) >> 3;
    const int r0 = s * chunk;
    const int r1 = min(R, r0 + chunk);
    float* slice = out + (size_t)c * R * 5;

    for (int k = r0 * 5 + t; k < r1 * 5; k += TPB) slice[k] = 0.f;
    __syncthreads();                    // drains the zero stores (vmcnt(0))

    const float sh = (float)(*ph), sw = (float)(*pw);
    const int kc = kcnt[c];
    for (int k = t; k < kc; k += TPB) {
        u64 e = kept[((size_t)c << 11) + k];
        int r = (int)(u32)e;
        if (r >= r0 && r < r1) {
            float v0, v1, v2, v3;
            decode_box(rois, loc, r, c + 1, sh, sw, v0, v1, v2, v3);
            float* p = slice + (size_t)r * 5;
            p[0] = v0; p[1] = v1; p[2] = v2; p[3] = v3;
            p[4] = __uint_as_float((u32)(e >> 32));
        }
    }
}

// --------------------------- fallback: R4 fused ----------------------------
#define NTH 1024
__global__ __launch_bounds__(NTH) void fused_kernel(
    const float* __restrict__ loc, const float* __restrict__ scores,
    const float* __restrict__ rois, const int* __restrict__ ph,
    const int* __restrict__ pw, float* __restrict__ out, int R)
{
    __shared__ u64 vkey[RMAX];
    __shared__ float2 p1[RMAX], p2[RMAX];
    __shared__ u64 chunk[64 * 33];
    __shared__ u64 rem[32];
    __shared__ int cnt;

    const int t = threadIdx.x;
    const int lane = t & 63;
    const int c = blockIdx.x + 1;
    const float sh = (float)(*ph), sw = (float)(*pw);

    if (t == 0) cnt = 0;
    if (t < 32) rem[t] = 0;
    __syncthreads();

    for (int r = t; r < R; r += NTH) {
        float p = softmax_p(scores, r, c);
        if (p > SCORE_THRESH) {
            int j = atomicAdd(&cnt, 1);
            vkey[j] = ((u64)(~__float_as_uint(p)) << 32) | (u32)r;
        }
    }
    __syncthreads();
    const int nv = cnt;
    const int nw = (nv + 63) >> 6;

    u64 kk0 = 0, kk1 = 0;
    int r0 = 0, r1 = 0;
    bool in0 = (t < nv), in1 = (t + NTH < nv);
    if (in0) kk0 = vkey[t];
    if (in1) kk1 = vkey[t + NTH];
#pragma unroll 8
    for (int i = 0; i < nv; ++i) {
        u64 k = vkey[i];
        r0 += (k < kk0);
        r1 += (k < kk1);
    }
    __syncthreads();

    for (int u = 0; u < 2; ++u) {
        bool act = u ? in1 : in0;
        if (act) {
            u64 kk = u ? kk1 : kk0;
            int rank = u ? r1 : r0;
            int r = (int)(kk & 0xffffffffu);
            float b0, b1, b2, b3;
            decode_box(rois, loc, r, c, sh, sw, b0, b1, b2, b3);
            vkey[rank] = kk;
            p1[rank] = make_float2(b0, b1);
            p2[rank] = make_float2(b2, b3);
        }
    }
    __syncthreads();

    for (int w = 0; w < nw; ++w) {
        int nwr = nw - w;
        u64 remw = rem[w];
        for (int task = t; task < (nwr << 6); task += NTH) {
            int vr = task >> 6, il = task & 63;
            int i = (w << 6) + il;
            u64 m = 0;
            if (i < nv && !((remw >> il) & 1ull)) {
                int v = w + vr;
                u64 rv = rem[v];
                if (~rv != 0ull) {
                    float2 a1 = p1[i], a2 = p2[i];
                    float iarea = (a2.x - a1.x) * (a2.y - a1.y);
                    int j0 = v << 6;
                    int jhi = min(64, nv - j0);
#pragma unroll 4
                    for (int jj = 0; jj < jhi; ++jj) {
                        float2 b1 = p1[j0 + jj], b2 = p2[j0 + jj];
                        float ty1 = fmaxf(a1.x, b1.x);
                        float tx1 = fmaxf(a1.y, b1.y);
                        float ty2 = fminf(a2.x, b2.x);
                        float tx2 = fminf(a2.y, b2.y);
                        float inter = fmaxf(ty2 - ty1, 0.f) * fmaxf(tx2 - tx1, 0.f);
                        float jarea = (b2.x - b1.x) * (b2.y - b1.y);
                        float uni = fmaxf(iarea + jarea - inter, 1e-10f);
                        if ((double)inter > IOU_MID * (double)uni) m |= 1ull << jj;
                    }
                    if (vr == 0)
                        m &= (il < 63) ? (~0ull << (il + 1)) : 0ull;
                }
            }
            chunk[il * 33 + vr] = m;
        }
        __syncthreads();

        u64 cand = chunk[lane * 33];
        u64 cur = rem[w];
        int remn = nv - (w << 6);
        u64 vb = (remn >= 64) ? ~0ull : ((1ull << remn) - 1ull);
        u64 avail = vb & ~cur;
        u64 kept = 0;
        while (avail) {
            int bb = __ffsll(avail) - 1;
            kept |= 1ull << bb;
            cur |= __shfl(cand, bb, 64);
            avail &= ~(cur | (1ull << bb));
        }
        int vr = t & 31, pg = t >> 5;
        if (vr >= 1 && vr < nwr) {
            u64 acc = 0, km = kept;
            int n = 0;
            while (km) {
                int bb = __ffsll(km) - 1;
                km &= km - 1;
                if ((n & 31) == pg) acc |= chunk[bb * 33 + vr];
                ++n;
            }
            if (acc) atomicOr(&rem[w + vr], acc);
        }
        if (t == 0) rem[w] = cur;
        __syncthreads();
    }

    u16* inv = (u16*)chunk;
    for (int r = t; r < R; r += NTH) inv[r] = 0xffffu;
    __syncthreads();
    for (int i = t; i < nv; i += NTH)
        if (!((rem[i >> 6] >> (i & 63)) & 1ull))
            inv[(int)(vkey[i] & 0xffffffffu)] = (u16)i;
    __syncthreads();
    float* slice = out + (size_t)(c - 1) * R * 5;
    for (int r = t; r < R; r += NTH) {
        int i = inv[r];
        float v0 = 0.f, v1 = 0.f, v2 = 0.f, v3 = 0.f, v4 = 0.f;
        if (i != 0xffff) {
            float2 a1 = p1[i], a2 = p2[i];
            v0 = a1.x; v1 = a1.y; v2 = a2.x; v3 = a2.y;
            v4 = __uint_as_float(~(u32)(vkey[i] >> 32));
        }
        float* p = slice + (size_t)r * 5;
        p[0] = v0; p[1] = v1; p[2] = v2; p[3] = v3; p[4] = v4;
    }
}

extern "C" void kernel_launch(void* const* d_in, const int* in_sizes, int n_in,
                              void* d_out, int out_size, void* d_ws, size_t ws_size,
                              hipStream_t stream) {
    const float* loc    = (const float*)d_in[0];   // (R, 84) f32
    const float* scores = (const float*)d_in[1];   // (R, 21) f32
    const float* rois   = (const float*)d_in[2];   // (R, 4)  f32
    const int*   ph     = (const int*)d_in[3];
    const int*   pw     = (const int*)d_in[4];
    float* out = (float*)d_out;                    // (20, R, 5) f32
    int R = in_sizes[2] / 4;

    // ws: M u64[20][2048*32] (compact) | ord u64[20][2048] | kept u64[20][2048]
    //     | nvv int[32] | kcnt int[32]
    size_t needM    = (size_t)NCO * RCAP * 32 * 8;  // 10.5 MB
    size_t needOrd  = (size_t)NCO * RCAP * 8;       // 328 KB
    size_t needKept = (size_t)NCO * RCAP * 8;       // 328 KB
    size_t need     = needM + needOrd + needKept + 256;

    if (R <= RCAP && ws_size >= need) {
        char* w   = (char*)d_ws;
        u64* M    = (u64*)w;
        u64* ordp = (u64*)(w + needM);
        u64* kept = (u64*)(w + needM + needOrd);
        int* nvv  = (int*)(w + needM + needOrd + needKept);
        int* kcnt = nvv + 32;
        sortmask_kernel<<<NCO * SUB, TPB, 0, stream>>>(loc, scores, rois, ph,
                                                       pw, ordp, nvv, M, R);
        resolve_kernel<<<NCO, TPB, 0, stream>>>(ordp, nvv, M, kept, kcnt, R);
        output_kernel<<<NCO * SUB, TPB, 0, stream>>>(loc, rois, ph, pw,
                                                     kept, kcnt, out, R);
    } else if (R <= RMAX) {
        fused_kernel<<<NCO, NTH, 0, stream>>>(loc, scores, rois, ph, pw, out, R);
    }
}

// Round 17
// 140.349 us; speedup vs baseline: 1.1686x; 1.1686x over previous
//
#include <hip/hip_runtime.h>
#include <math.h>

#define NCLS 21
#define NCO 20
#define SUB 8                  // blocks per class in mask/resolveout kernels
#define TPB 256
#define STH 1024
#define RCAP 2048
#define RMAX 2000
#define LDSW 7680              // u64 capacity of mask LDS (60 KB): nv<=960
#define SCORE_THRESH 0.05f

typedef unsigned long long u64;
typedef unsigned int u32;
typedef unsigned short u16;

// Exact equivalent of (f32_div(inter,uni) > 0.3f):  inter > IOU_MID * uni in f64.
// 0.3f = 10066330*2^-25; midpoint to next float = 20132661*2^-26. RN tie at the
// midpoint rounds to even (0.3f) -> false, matching strict ">". 25b x 24b exact in f64.
#define IOU_MID (20132661.0 / 67108864.0)

__device__ __forceinline__ u64 readlane64(u64 v, int l) {
    u32 lo = (u32)__builtin_amdgcn_readlane((int)(u32)v, l);
    u32 hi = (u32)__builtin_amdgcn_readlane((int)(u32)(v >> 32), l);
    return ((u64)hi << 32) | lo;
}
__device__ __forceinline__ float readlanef(float v, int l) {
    return __uint_as_float((u32)__builtin_amdgcn_readlane((int)__float_as_uint(v), l));
}
__device__ __forceinline__ u64 shflxor64(u64 v, int m) {
    u32 lo = (u32)__shfl_xor((int)(u32)v, m, 64);
    u32 hi = (u32)__shfl_xor((int)(u32)(v >> 32), m, 64);
    return ((u64)hi << 32) | lo;
}

// Compact upper-triangle mask layout, per class:
// chunk ic (64 rows) starts at coff(ic); row (ic<<6)+il has W=nw-ic words
// (words v=ic..nw-1) at coff(ic) + il*W + (v-ic). Total = coff(nw) words.
__device__ __forceinline__ int coff(int ic, int nw) {
    return ((ic * nw - ((ic * (ic - 1)) >> 1)) << 6);
}

// Reference-exact box decode (absmax 0.0 through R1-R16).
__device__ __forceinline__ void decode_box(
    const float* __restrict__ rois, const float* __restrict__ loc,
    int r, int cls, float sh, float sw,
    float& by1, float& bx1, float& by2, float& bx2)
{
    float4 rb = *(const float4*)(rois + r * 4);
    float y1 = rb.x, x1 = rb.y, y2 = rb.z, x2 = rb.w;
    float h = y2 - y1, w = x2 - x1;
    float cy = y1 + 0.5f * h, cx = x1 + 0.5f * w;
    float4 l4 = *(const float4*)(loc + r * (NCLS * 4) + cls * 4);
    float dy = l4.x * 0.1f, dx = l4.y * 0.1f;
    float dh = l4.z * 0.2f, dw = l4.w * 0.2f;
    float ncy = dy * h + cy, ncx = dx * w + cx;
    float nh = expf(dh) * h, nw = expf(dw) * w;
    by1 = fminf(fmaxf(ncy - 0.5f * nh, 0.f), sh);
    bx1 = fminf(fmaxf(ncx - 0.5f * nw, 0.f), sw);
    by2 = fminf(fmaxf(ncy + 0.5f * nh, 0.f), sh);
    bx2 = fminf(fmaxf(ncx + 0.5f * nw, 0.f), sw);
}

// Reference-exact softmax prob (vectorized loads; float op ORDER k=0..20 kept
// identical to prior rounds: max then exp-sum in index order).
__device__ __forceinline__ float softmax_p(
    const float* __restrict__ scores, int r, int cls)
{
    const float* srow = scores + r * NCLS;
    float s[NCLS];
    float4 a0 = *(const float4*)(srow);
    float4 a1 = *(const float4*)(srow + 4);
    float4 a2 = *(const float4*)(srow + 8);
    float4 a3 = *(const float4*)(srow + 12);
    float4 a4 = *(const float4*)(srow + 16);
    s[0]=a0.x; s[1]=a0.y; s[2]=a0.z; s[3]=a0.w;
    s[4]=a1.x; s[5]=a1.y; s[6]=a1.z; s[7]=a1.w;
    s[8]=a2.x; s[9]=a2.y; s[10]=a2.z; s[11]=a2.w;
    s[12]=a3.x; s[13]=a3.y; s[14]=a3.z; s[15]=a3.w;
    s[16]=a4.x; s[17]=a4.y; s[18]=a4.z; s[19]=a4.w;
    s[20]=srow[20];
    float m = -INFINITY;
#pragma unroll
    for (int k = 0; k < NCLS; ++k) m = fmaxf(m, s[k]);
    float sum = 0.f, ec = 0.f;
#pragma unroll
    for (int k = 0; k < NCLS; ++k) {
        float e = expf(s[k] - m);
        sum += e;
        if (k == cls) ec = e;
    }
    return ec / sum;
}

// ---------------------------------------------------------------------------
// K1 sort: 20 blocks x 1024 (R13/R15-proven). Softmax + valid-only
// compaction, rank via LDS same-address broadcast. key=(~p_bits)<<32|r.
// ---------------------------------------------------------------------------
__global__ __launch_bounds__(STH) void sort_kernel(
    const float* __restrict__ scores, u64* __restrict__ ord,
    int* __restrict__ nvv, int R)
{
    __shared__ u64 vkey[RCAP];
    __shared__ int cnt;
    const int t = threadIdx.x;
    const int c = blockIdx.x;          // class-1 index 0..19
    if (t == 0) cnt = 0;
    __syncthreads();

    for (int r = t; r < R; r += STH) {
        float p = softmax_p(scores, r, c + 1);
        if (p > SCORE_THRESH) {
            int j = atomicAdd(&cnt, 1);
            vkey[j] = ((u64)(~__float_as_uint(p)) << 32) | (u32)r;
        }
    }
    __syncthreads();
    const int nv = cnt;
    if (t == 0) nvv[c] = nv;

    for (int ibase = 0; ibase < nv; ibase += STH) {
        int i = ibase + t;
        if (i < nv) {
            u64 kj = vkey[i];
            int rank = 0;
#pragma unroll 4
            for (int j = 0; j < nv; ++j)
                rank += (vkey[j] < kj);    // same-address LDS broadcast
            ord[((size_t)c << 11) + rank] = kj;
        }
    }
}

// ---------------------------------------------------------------------------
// K2 mask: 160 blocks x 256 (R12-R15-proven; wide — R11/R16 lesson: neither
// mask nor sort tolerates being narrowed/duplicated). Sorted boxes decoded to
// LDS once per block; wave-tasks = upper-tri (row-chunk ic, word v) pairs;
// writes COMPACT layout.
// ---------------------------------------------------------------------------
__global__ __launch_bounds__(TPB) void mask_kernel(
    const float* __restrict__ loc, const float* __restrict__ rois,
    const int* __restrict__ ph, const int* __restrict__ pw,
    const u64* __restrict__ ord, const int* __restrict__ nvv,
    u64* __restrict__ M, int R)
{
    __shared__ float4 pb[RCAP];        // 32 KB sorted boxes
    __shared__ float ar[RCAP];         // 8 KB areas
    const int t = threadIdx.x;
    const int c = blockIdx.x >> 3;
    const int s = blockIdx.x & 7;
    const int nv = nvv[c];
    const int nw = (nv + 63) >> 6;
    const float sh = (float)(*ph), sw = (float)(*pw);

    for (int i = t; i < nv; i += TPB) {
        u64 key = ord[((size_t)c << 11) + i];
        int r = (int)(u32)key;
        float a0, a1, a2, a3;
        decode_box(rois, loc, r, c + 1, sh, sw, a0, a1, a2, a3);
        pb[i] = make_float4(a0, a1, a2, a3);
        ar[i] = (a2 - a0) * (a3 - a1);
    }
    __syncthreads();

    const int lane = t & 63;
    const int wid = (s << 2) | (t >> 6);     // 0..31 waves per class
    const int ntasks = nw * (nw + 1) / 2;
    u64* Mc = M + ((size_t)c << 16);
    for (int task = wid; task < ntasks; task += SUB * 4) {
        int ic = 0, rm = task;
        while (rm >= nw - ic) { rm -= nw - ic; ++ic; }  // uniform, <=32 iters
        int v = ic + rm;
        int i = (ic << 6) + lane;
        float4 a = pb[i];                    // garbage if i>=nv (not stored)
        float iarea = ar[i];
        float4 rj = pb[(v << 6) + lane];     // loads executed by all lanes
        float ja_l = ar[(v << 6) + lane];
        int jcnt = min(64, nv - (v << 6));
        u64 m = 0;
        for (int jj = 0; jj < jcnt; ++jj) {
            float jy1 = readlanef(rj.x, jj);
            float jx1 = readlanef(rj.y, jj);
            float jy2 = readlanef(rj.z, jj);
            float jx2 = readlanef(rj.w, jj);
            float ja  = readlanef(ja_l, jj);
            float ty1 = fmaxf(a.x, jy1);
            float tx1 = fmaxf(a.y, jx1);
            float ty2 = fminf(a.z, jy2);
            float tx2 = fminf(a.w, jx2);
            float inter = fmaxf(ty2 - ty1, 0.f) * fmaxf(tx2 - tx1, 0.f);
            float uni = fmaxf(iarea + ja - inter, 1e-10f);
            if ((double)inter > IOU_MID * (double)uni) m |= 1ull << jj;
        }
        if (v == ic) m &= (lane < 63) ? (~0ull << (lane + 1)) : 0ull;
        int W = nw - ic;
        if (i < nv) Mc[coff(ic, nw) + lane * W + (v - ic)] = m;
    }
}

// ---------------------------------------------------------------------------
// K3 resolveout: 160 blocks x 256 (8 sub-blocks per class). Each sub-block
// REDUNDANTLY stages the class's compact mask (L2-hot after the first) and
// runs the R15-verbatim ballot-Gauss-Seidel resolve (pure function of M ->
// deterministic), then zeroes + scatters its 1/8 output slice from the
// in-LDS keep bits. This removes R15's separate 20-block resolve dispatch,
// its launch/ramp floor, and the kept-list global round-trip (R15 isolation:
// three different resolve cores all pinned at ~40us as a 20-block dispatch).
// ---------------------------------------------------------------------------
__global__ __launch_bounds__(TPB) void resolveout_kernel(
    const float* __restrict__ loc, const float* __restrict__ rois,
    const int* __restrict__ ph, const int* __restrict__ pw,
    const u64* __restrict__ ord, const int* __restrict__ nvv,
    const u64* __restrict__ M, float* __restrict__ out, int R)
{
    __shared__ u64 mlds[LDSW];         // 60 KB compact mask
    __shared__ u64 keptw[32];
    const int t = threadIdx.x;
    const int c = blockIdx.x >> 3;
    const int s = blockIdx.x & 7;
    const int nv = nvv[c];
    const int nw = (nv + 63) >> 6;
    const u64* Mc = M + ((size_t)c << 16);
    const int S = coff(nw, nw);
    const bool lds_ok = (S <= LDSW);
    if (t < 32) keptw[t] = 0;

    if (lds_ok) {
        for (int base = 0; base < S; base += 2048) {
            u64 v[8];
#pragma unroll
            for (int j = 0; j < 8; ++j) {      // 8 independent coalesced loads
                int k = base + (j << 8) + t;
                v[j] = (k < S) ? Mc[k] : 0ull;
            }
#pragma unroll
            for (int j = 0; j < 8; ++j) {
                int k = base + (j << 8) + t;
                if (k < S) mlds[k] = v[j];
            }
        }
    }
    __syncthreads();

#define MLD(idx) (lds_ok ? mlds[(idx)] : Mc[(idx)])
    if (t < 64) {
        const int lane = t;
        u64 remreg = 0;                     // lane l owns removed-word l
        for (int w = 0; w < nw; ++w) {
            const int W = nw - w;
            const int cb = coff(w, nw);
            int i = (w << 6) + lane;
            u64 cw = (i < nv) ? MLD(cb + lane * W) : 0ull;   // diagonal word
            int remn = nv - (w << 6);
            u64 vb = (remn >= 64) ? ~0ull : ((1ull << remn) - 1ull);
            u64 cand = vb & ~readlane64(remreg, w);
            u64 X = cand;
            if (X) {
                // in-word greedy fixpoint (ballot Jacobi; upper-triangularity
                // makes contrib bit l come only from rows j<l => fixpoint =
                // greedy by index induction).
                for (int it = 0; it < 64; ++it) {
                    u64 contrib = ((X >> lane) & 1ull) ? cw : 0ull;
#pragma unroll
                    for (int d = 1; d < 64; d <<= 1)
                        contrib |= shflxor64(contrib, d);
                    bool keep = ((cand >> lane) & 1ull) &&
                                !((contrib >> lane) & 1ull);
                    u64 Xn = __ballot(keep);
                    if (Xn == X) break;
                    X = Xn;
                }
                if (lane == 0) keptw[w] = X;
                bool lact = (lane > w) && (lane < nw);
                u64 km = X, acc = 0;
                while (km) {                 // wave-uniform ffs (X uniform)
                    int il = __ffsll(km) - 1;
                    km &= km - 1;
                    if (lact) acc |= MLD(cb + il * W + (lane - w));
                }
                if (lact) remreg |= acc;
            }
        }
    }
#undef MLD
    __syncthreads();

    // Output: zero this sub-block's slice, barrier (drains stores), scatter
    // kept rows whose roi index falls in range (decode recompute + prob bits).
    const int chunk = (R + 7) >> 3;
    const int r0 = s * chunk;
    const int r1 = min(R, r0 + chunk);
    float* slice = out + (size_t)c * R * 5;
    for (int k = r0 * 5 + t; k < r1 * 5; k += TPB) slice[k] = 0.f;
    __syncthreads();                    // drains the zero stores (vmcnt(0))

    const float sh = (float)(*ph), sw = (float)(*pw);
    for (int i = t; i < nv; i += TPB) {
        if ((keptw[i >> 6] >> (i & 63)) & 1ull) {
            u64 key = ord[((size_t)c << 11) + i];
            int r = (int)(u32)key;
            if (r >= r0 && r < r1) {
                float v0, v1, v2, v3;
                decode_box(rois, loc, r, c + 1, sh, sw, v0, v1, v2, v3);
                float* p = slice + (size_t)r * 5;
                p[0] = v0; p[1] = v1; p[2] = v2; p[3] = v3;
                p[4] = __uint_as_float(~(u32)(key >> 32));
            }
        }
    }
}

// --------------------------- fallback: R4 fused ----------------------------
#define NTH 1024
__global__ __launch_bounds__(NTH) void fused_kernel(
    const float* __restrict__ loc, const float* __restrict__ scores,
    const float* __restrict__ rois, const int* __restrict__ ph,
    const int* __restrict__ pw, float* __restrict__ out, int R)
{
    __shared__ u64 vkey[RMAX];
    __shared__ float2 p1[RMAX], p2[RMAX];
    __shared__ u64 chunk[64 * 33];
    __shared__ u64 rem[32];
    __shared__ int cnt;

    const int t = threadIdx.x;
    const int lane = t & 63;
    const int c = blockIdx.x + 1;
    const float sh = (float)(*ph), sw = (float)(*pw);

    if (t == 0) cnt = 0;
    if (t < 32) rem[t] = 0;
    __syncthreads();

    for (int r = t; r < R; r += NTH) {
        float p = softmax_p(scores, r, c);
        if (p > SCORE_THRESH) {
            int j = atomicAdd(&cnt, 1);
            vkey[j] = ((u64)(~__float_as_uint(p)) << 32) | (u32)r;
        }
    }
    __syncthreads();
    const int nv = cnt;
    const int nw = (nv + 63) >> 6;

    u64 kk0 = 0, kk1 = 0;
    int r0 = 0, r1 = 0;
    bool in0 = (t < nv), in1 = (t + NTH < nv);
    if (in0) kk0 = vkey[t];
    if (in1) kk1 = vkey[t + NTH];
#pragma unroll 8
    for (int i = 0; i < nv; ++i) {
        u64 k = vkey[i];
        r0 += (k < kk0);
        r1 += (k < kk1);
    }
    __syncthreads();

    for (int u = 0; u < 2; ++u) {
        bool act = u ? in1 : in0;
        if (act) {
            u64 kk = u ? kk1 : kk0;
            int rank = u ? r1 : r0;
            int r = (int)(kk & 0xffffffffu);
            float b0, b1, b2, b3;
            decode_box(rois, loc, r, c, sh, sw, b0, b1, b2, b3);
            vkey[rank] = kk;
            p1[rank] = make_float2(b0, b1);
            p2[rank] = make_float2(b2, b3);
        }
    }
    __syncthreads();

    for (int w = 0; w < nw; ++w) {
        int nwr = nw - w;
        u64 remw = rem[w];
        for (int task = t; task < (nwr << 6); task += NTH) {
            int vr = task >> 6, il = task & 63;
            int i = (w << 6) + il;
            u64 m = 0;
            if (i < nv && !((remw >> il) & 1ull)) {
                int v = w + vr;
                u64 rv = rem[v];
                if (~rv != 0ull) {
                    float2 a1 = p1[i], a2 = p2[i];
                    float iarea = (a2.x - a1.x) * (a2.y - a1.y);
                    int j0 = v << 6;
                    int jhi = min(64, nv - j0);
#pragma unroll 4
                    for (int jj = 0; jj < jhi; ++jj) {
                        float2 b1 = p1[j0 + jj], b2 = p2[j0 + jj];
                        float ty1 = fmaxf(a1.x, b1.x);
                        float tx1 = fmaxf(a1.y, b1.y);
                        float ty2 = fminf(a2.x, b2.x);
                        float tx2 = fminf(a2.y, b2.y);
                        float inter = fmaxf(ty2 - ty1, 0.f) * fmaxf(tx2 - tx1, 0.f);
                        float jarea = (b2.x - b1.x) * (b2.y - b1.y);
                        float uni = fmaxf(iarea + jarea - inter, 1e-10f);
                        if ((double)inter > IOU_MID * (double)uni) m |= 1ull << jj;
                    }
                    if (vr == 0)
                        m &= (il < 63) ? (~0ull << (il + 1)) : 0ull;
                }
            }
            chunk[il * 33 + vr] = m;
        }
        __syncthreads();

        u64 cand = chunk[lane * 33];
        u64 cur = rem[w];
        int remn = nv - (w << 6);
        u64 vb = (remn >= 64) ? ~0ull : ((1ull << remn) - 1ull);
        u64 avail = vb & ~cur;
        u64 kept = 0;
        while (avail) {
            int bb = __ffsll(avail) - 1;
            kept |= 1ull << bb;
            cur |= __shfl(cand, bb, 64);
            avail &= ~(cur | (1ull << bb));
        }
        int vr = t & 31, pg = t >> 5;
        if (vr >= 1 && vr < nwr) {
            u64 acc = 0, km = kept;
            int n = 0;
            while (km) {
                int bb = __ffsll(km) - 1;
                km &= km - 1;
                if ((n & 31) == pg) acc |= chunk[bb * 33 + vr];
                ++n;
            }
            if (acc) atomicOr(&rem[w + vr], acc);
        }
        if (t == 0) rem[w] = cur;
        __syncthreads();
    }

    u16* inv = (u16*)chunk;
    for (int r = t; r < R; r += NTH) inv[r] = 0xffffu;
    __syncthreads();
    for (int i = t; i < nv; i += NTH)
        if (!((rem[i >> 6] >> (i & 63)) & 1ull))
            inv[(int)(vkey[i] & 0xffffffffu)] = (u16)i;
    __syncthreads();
    float* slice = out + (size_t)(c - 1) * R * 5;
    for (int r = t; r < R; r += NTH) {
        int i = inv[r];
        float v0 = 0.f, v1 = 0.f, v2 = 0.f, v3 = 0.f, v4 = 0.f;
        if (i != 0xffff) {
            float2 a1 = p1[i], a2 = p2[i];
            v0 = a1.x; v1 = a1.y; v2 = a2.x; v3 = a2.y;
            v4 = __uint_as_float(~(u32)(vkey[i] >> 32));
        }
        float* p = slice + (size_t)r * 5;
        p[0] = v0; p[1] = v1; p[2] = v2; p[3] = v3; p[4] = v4;
    }
}

extern "C" void kernel_launch(void* const* d_in, const int* in_sizes, int n_in,
                              void* d_out, int out_size, void* d_ws, size_t ws_size,
                              hipStream_t stream) {
    const float* loc    = (const float*)d_in[0];   // (R, 84) f32
    const float* scores = (const float*)d_in[1];   // (R, 21) f32
    const float* rois   = (const float*)d_in[2];   // (R, 4)  f32
    const int*   ph     = (const int*)d_in[3];
    const int*   pw     = (const int*)d_in[4];
    float* out = (float*)d_out;                    // (20, R, 5) f32
    int R = in_sizes[2] / 4;

    // ws: M u64[20][2048*32] (compact) | ord u64[20][2048] | nvv int[32]
    size_t needM   = (size_t)NCO * RCAP * 32 * 8;  // 10.5 MB
    size_t needOrd = (size_t)NCO * RCAP * 8;       // 328 KB
    size_t need    = needM + needOrd + 128;

    if (R <= RCAP && ws_size >= need) {
        char* w   = (char*)d_ws;
        u64* M    = (u64*)w;
        u64* ordp = (u64*)(w + needM);
        int* nvv  = (int*)(w + needM + needOrd);
        sort_kernel<<<NCO, STH, 0, stream>>>(scores, ordp, nvv, R);
        mask_kernel<<<NCO * SUB, TPB, 0, stream>>>(loc, rois, ph, pw, ordp, nvv,
                                                   M, R);
        resolveout_kernel<<<NCO * SUB, TPB, 0, stream>>>(loc, rois, ph, pw,
                                                         ordp, nvv, M, out, R);
    } else if (R <= RMAX) {
        fused_kernel<<<NCO, NTH, 0, stream>>>(loc, scores, rois, ph, pw, out, R);
    }
}

// Round 18
// 127.379 us; speedup vs baseline: 1.2876x; 1.1018x over previous
//
#include <hip/hip_runtime.h>
#include <math.h>

#define NCLS 21
#define NCO 20
#define SUB 8                  // blocks per class in mask/resolveout kernels
#define TPB 256
#define STH 1024
#define RCAP 2048
#define RMAX 2000
#define LDSW 7680              // u64 capacity of mask LDS (60 KB): nv<=960
#define SCORE_THRESH 0.05f

typedef unsigned long long u64;
typedef unsigned int u32;
typedef unsigned short u16;

// Exact equivalent of (f32_div(inter,uni) > 0.3f):  inter > IOU_MID * uni in f64.
// 0.3f = 10066330*2^-25; midpoint to next float = 20132661*2^-26. RN tie at the
// midpoint rounds to even (0.3f) -> false, matching strict ">". 25b x 24b exact in f64.
#define IOU_MID (20132661.0 / 67108864.0)

__device__ __forceinline__ u64 readlane64(u64 v, int l) {
    u32 lo = (u32)__builtin_amdgcn_readlane((int)(u32)v, l);
    u32 hi = (u32)__builtin_amdgcn_readlane((int)(u32)(v >> 32), l);
    return ((u64)hi << 32) | lo;
}
__device__ __forceinline__ float readlanef(float v, int l) {
    return __uint_as_float((u32)__builtin_amdgcn_readlane((int)__float_as_uint(v), l));
}
__device__ __forceinline__ u64 shflxor64(u64 v, int m) {
    u32 lo = (u32)__shfl_xor((int)(u32)v, m, 64);
    u32 hi = (u32)__shfl_xor((int)(u32)(v >> 32), m, 64);
    return ((u64)hi << 32) | lo;
}

// Compact upper-triangle mask layout, per class:
// chunk ic (64 rows) starts at coff(ic); row (ic<<6)+il has W=nw-ic words
// (words v=ic..nw-1) at coff(ic) + il*W + (v-ic). Total = coff(nw) words.
__device__ __forceinline__ int coff(int ic, int nw) {
    return ((ic * nw - ((ic * (ic - 1)) >> 1)) << 6);
}

// Reference-exact box decode (absmax 0.0 through R1-R17).
__device__ __forceinline__ void decode_box(
    const float* __restrict__ rois, const float* __restrict__ loc,
    int r, int cls, float sh, float sw,
    float& by1, float& bx1, float& by2, float& bx2)
{
    float4 rb = *(const float4*)(rois + r * 4);
    float y1 = rb.x, x1 = rb.y, y2 = rb.z, x2 = rb.w;
    float h = y2 - y1, w = x2 - x1;
    float cy = y1 + 0.5f * h, cx = x1 + 0.5f * w;
    float4 l4 = *(const float4*)(loc + r * (NCLS * 4) + cls * 4);
    float dy = l4.x * 0.1f, dx = l4.y * 0.1f;
    float dh = l4.z * 0.2f, dw = l4.w * 0.2f;
    float ncy = dy * h + cy, ncx = dx * w + cx;
    float nh = expf(dh) * h, nw = expf(dw) * w;
    by1 = fminf(fmaxf(ncy - 0.5f * nh, 0.f), sh);
    bx1 = fminf(fmaxf(ncx - 0.5f * nw, 0.f), sw);
    by2 = fminf(fmaxf(ncy + 0.5f * nh, 0.f), sh);
    bx2 = fminf(fmaxf(ncx + 0.5f * nw, 0.f), sw);
}

// Reference-exact softmax prob (vectorized loads; float op ORDER k=0..20 kept
// identical to prior rounds: max then exp-sum in index order).
__device__ __forceinline__ float softmax_p(
    const float* __restrict__ scores, int r, int cls)
{
    const float* srow = scores + r * NCLS;
    float s[NCLS];
    float4 a0 = *(const float4*)(srow);
    float4 a1 = *(const float4*)(srow + 4);
    float4 a2 = *(const float4*)(srow + 8);
    float4 a3 = *(const float4*)(srow + 12);
    float4 a4 = *(const float4*)(srow + 16);
    s[0]=a0.x; s[1]=a0.y; s[2]=a0.z; s[3]=a0.w;
    s[4]=a1.x; s[5]=a1.y; s[6]=a1.z; s[7]=a1.w;
    s[8]=a2.x; s[9]=a2.y; s[10]=a2.z; s[11]=a2.w;
    s[12]=a3.x; s[13]=a3.y; s[14]=a3.z; s[15]=a3.w;
    s[16]=a4.x; s[17]=a4.y; s[18]=a4.z; s[19]=a4.w;
    s[20]=srow[20];
    float m = -INFINITY;
#pragma unroll
    for (int k = 0; k < NCLS; ++k) m = fmaxf(m, s[k]);
    float sum = 0.f, ec = 0.f;
#pragma unroll
    for (int k = 0; k < NCLS; ++k) {
        float e = expf(s[k] - m);
        sum += e;
        if (k == cls) ec = e;
    }
    return ec / sum;
}

// ---------------------------------------------------------------------------
// K1 sort: 20 blocks x 1024 (R13/R15-proven), with BALLOT COMPACTION: one
// LDS atomic per wave-iteration instead of one per valid row (R17 inference:
// ~2000 serialized same-address LDS atomicAdds ~ 10-15us). Within a wave the
// active lanes of each loop iteration form a lane-prefix (r = t + k*1024
// increases with lane), so lane 0 is always a valid leader.
// ---------------------------------------------------------------------------
__global__ __launch_bounds__(STH) void sort_kernel(
    const float* __restrict__ scores, u64* __restrict__ ord,
    int* __restrict__ nvv, int R)
{
    __shared__ u64 vkey[RCAP];
    __shared__ int cnt;
    const int t = threadIdx.x;
    const int c = blockIdx.x;          // class-1 index 0..19
    const int lane = t & 63;
    if (t == 0) cnt = 0;
    __syncthreads();

    for (int r = t; r < R; r += STH) {
        float p = softmax_p(scores, r, c + 1);
        bool valid = (p > SCORE_THRESH);
        u64 key = ((u64)(~__float_as_uint(p)) << 32) | (u32)r;
        u64 bal = __ballot(valid);
        if (bal) {
            int nb = (int)__popcll(bal);
            int base = 0;
            if (lane == 0) base = atomicAdd(&cnt, nb);
            base = __shfl(base, 0, 64);          // lane 0 active (prefix)
            if (valid)
                vkey[base + (int)__popcll(bal & ((1ull << lane) - 1ull))] = key;
        }
    }
    __syncthreads();
    const int nv = cnt;
    if (t == 0) nvv[c] = nv;

    for (int ibase = 0; ibase < nv; ibase += STH) {
        int i = ibase + t;
        if (i < nv) {
            u64 kj = vkey[i];
            int rank = 0;
#pragma unroll 4
            for (int j = 0; j < nv; ++j)
                rank += (vkey[j] < kj);    // same-address LDS broadcast
            ord[((size_t)c << 11) + rank] = kj;
        }
    }
}

// ---------------------------------------------------------------------------
// K2 mask: 160 blocks x 256 (R12-R17-proven; wide — R11/R16 lesson). Sorted
// boxes decoded to LDS once per block; wave-tasks = upper-tri (row-chunk ic,
// word v) pairs; writes COMPACT layout.
// ---------------------------------------------------------------------------
__global__ __launch_bounds__(TPB) void mask_kernel(
    const float* __restrict__ loc, const float* __restrict__ rois,
    const int* __restrict__ ph, const int* __restrict__ pw,
    const u64* __restrict__ ord, const int* __restrict__ nvv,
    u64* __restrict__ M, int R)
{
    __shared__ float4 pb[RCAP];        // 32 KB sorted boxes
    __shared__ float ar[RCAP];         // 8 KB areas
    const int t = threadIdx.x;
    const int c = blockIdx.x >> 3;
    const int s = blockIdx.x & 7;
    const int nv = nvv[c];
    const int nw = (nv + 63) >> 6;
    const float sh = (float)(*ph), sw = (float)(*pw);

    for (int i = t; i < nv; i += TPB) {
        u64 key = ord[((size_t)c << 11) + i];
        int r = (int)(u32)key;
        float a0, a1, a2, a3;
        decode_box(rois, loc, r, c + 1, sh, sw, a0, a1, a2, a3);
        pb[i] = make_float4(a0, a1, a2, a3);
        ar[i] = (a2 - a0) * (a3 - a1);
    }
    __syncthreads();

    const int lane = t & 63;
    const int wid = (s << 2) | (t >> 6);     // 0..31 waves per class
    const int ntasks = nw * (nw + 1) / 2;
    u64* Mc = M + ((size_t)c << 16);
    for (int task = wid; task < ntasks; task += SUB * 4) {
        int ic = 0, rm = task;
        while (rm >= nw - ic) { rm -= nw - ic; ++ic; }  // uniform, <=32 iters
        int v = ic + rm;
        int i = (ic << 6) + lane;
        float4 a = pb[i];                    // garbage if i>=nv (not stored)
        float iarea = ar[i];
        float4 rj = pb[(v << 6) + lane];     // loads executed by all lanes
        float ja_l = ar[(v << 6) + lane];
        int jcnt = min(64, nv - (v << 6));
        u64 m = 0;
        for (int jj = 0; jj < jcnt; ++jj) {
            float jy1 = readlanef(rj.x, jj);
            float jx1 = readlanef(rj.y, jj);
            float jy2 = readlanef(rj.z, jj);
            float jx2 = readlanef(rj.w, jj);
            float ja  = readlanef(ja_l, jj);
            float ty1 = fmaxf(a.x, jy1);
            float tx1 = fmaxf(a.y, jx1);
            float ty2 = fminf(a.z, jy2);
            float tx2 = fminf(a.w, jx2);
            float inter = fmaxf(ty2 - ty1, 0.f) * fmaxf(tx2 - tx1, 0.f);
            float uni = fmaxf(iarea + ja - inter, 1e-10f);
            if ((double)inter > IOU_MID * (double)uni) m |= 1ull << jj;
        }
        if (v == ic) m &= (lane < 63) ? (~0ull << (lane + 1)) : 0ull;
        int W = nw - ic;
        if (i < nv) Mc[coff(ic, nw) + lane * W + (v - ic)] = m;
    }
}

// ---------------------------------------------------------------------------
// K3 resolveout: 160 blocks x 256 (R17 structure). Each sub-block stages the
// class's compact mask and runs the resolve, then zeroes + scatters its 1/8
// output slice. R18 change: propagation is 8-WIDE BATCHED (R17 post-mortem:
// the serial one-dependent-ds_read-per-kept-row loop at ~130 cyc each was the
// ~25us invariant across R13/R15/R17's resolve cores; batch loads are
// independent -> pipelined). Generic-lambda hoists the LDS/global select so
// the hot path is pure ds_read.
// ---------------------------------------------------------------------------
__global__ __launch_bounds__(TPB) void resolveout_kernel(
    const float* __restrict__ loc, const float* __restrict__ rois,
    const int* __restrict__ ph, const int* __restrict__ pw,
    const u64* __restrict__ ord, const int* __restrict__ nvv,
    const u64* __restrict__ M, float* __restrict__ out, int R)
{
    __shared__ u64 mlds[LDSW];         // 60 KB compact mask
    __shared__ u64 keptw[32];
    const int t = threadIdx.x;
    const int c = blockIdx.x >> 3;
    const int s = blockIdx.x & 7;
    const int nv = nvv[c];
    const int nw = (nv + 63) >> 6;
    const u64* Mc = M + ((size_t)c << 16);
    const int S = coff(nw, nw);
    const bool lds_ok = (S <= LDSW);
    if (t < 32) keptw[t] = 0;

    if (lds_ok) {
        for (int base = 0; base < S; base += 2048) {
            u64 v[8];
#pragma unroll
            for (int j = 0; j < 8; ++j) {      // 8 independent coalesced loads
                int k = base + (j << 8) + t;
                v[j] = (k < S) ? Mc[k] : 0ull;
            }
#pragma unroll
            for (int j = 0; j < 8; ++j) {
                int k = base + (j << 8) + t;
                if (k < S) mlds[k] = v[j];
            }
        }
    }
    __syncthreads();

    if (t < 64) {
        const int lane = t;
        auto core = [&](const auto* B) {
            u64 remreg = 0;                 // lane l owns removed-word l
            for (int w = 0; w < nw; ++w) {
                const int W = nw - w;
                const int cb = coff(w, nw);
                int i = (w << 6) + lane;
                u64 cw = (i < nv) ? B[cb + lane * W] : 0ull;   // diagonal word
                int remn = nv - (w << 6);
                u64 vb = (remn >= 64) ? ~0ull : ((1ull << remn) - 1ull);
                u64 cand = vb & ~readlane64(remreg, w);
                u64 X = cand;
                if (X) {
                    // in-word greedy fixpoint (ballot Jacobi; strict upper
                    // triangle => contrib bit l only from rows j<l =>
                    // fixpoint = greedy by index induction). R15-proven.
                    for (int it = 0; it < 64; ++it) {
                        u64 contrib = ((X >> lane) & 1ull) ? cw : 0ull;
#pragma unroll
                        for (int d = 1; d < 64; d <<= 1)
                            contrib |= shflxor64(contrib, d);
                        bool keep = ((cand >> lane) & 1ull) &&
                                    !((contrib >> lane) & 1ull);
                        u64 Xn = __ballot(keep);
                        if (Xn == X) break;
                        X = Xn;
                    }
                    if (lane == 0) keptw[w] = X;
                    // 8-wide batched propagation into later rem words
                    // (lane v owns word v); km=X is wave-uniform.
                    bool lact = (lane > w) && (lane < nw);
                    u64 km = X, acc = 0;
                    while (km) {
                        int bs[8];
#pragma unroll
                        for (int g = 0; g < 8; ++g) {
                            bs[g] = km ? (__ffsll(km) - 1) : -1;
                            if (km) km &= km - 1;
                        }
                        u64 tmp[8];
#pragma unroll
                        for (int g = 0; g < 8; ++g)
                            tmp[g] = (bs[g] >= 0 && lact)
                                ? B[cb + bs[g] * W + (lane - w)] : 0ull;
#pragma unroll
                        for (int g = 0; g < 8; ++g) acc |= tmp[g];
                    }
                    if (lact) remreg |= acc;
                }
            }
        };
        if (lds_ok) core(mlds); else core(Mc);
    }
    __syncthreads();

    // Output: zero this sub-block's slice, barrier (drains stores), scatter
    // kept rows whose roi index falls in range (decode recompute + prob bits).
    const int chunk = (R + 7) >> 3;
    const int r0 = s * chunk;
    const int r1 = min(R, r0 + chunk);
    float* slice = out + (size_t)c * R * 5;
    for (int k = r0 * 5 + t; k < r1 * 5; k += TPB) slice[k] = 0.f;
    __syncthreads();                    // drains the zero stores (vmcnt(0))

    const float sh = (float)(*ph), sw = (float)(*pw);
    for (int i = t; i < nv; i += TPB) {
        if ((keptw[i >> 6] >> (i & 63)) & 1ull) {
            u64 key = ord[((size_t)c << 11) + i];
            int r = (int)(u32)key;
            if (r >= r0 && r < r1) {
                float v0, v1, v2, v3;
                decode_box(rois, loc, r, c + 1, sh, sw, v0, v1, v2, v3);
                float* p = slice + (size_t)r * 5;
                p[0] = v0; p[1] = v1; p[2] = v2; p[3] = v3;
                p[4] = __uint_as_float(~(u32)(key >> 32));
            }
        }
    }
}

// --------------------------- fallback: R4 fused ----------------------------
#define NTH 1024
__global__ __launch_bounds__(NTH) void fused_kernel(
    const float* __restrict__ loc, const float* __restrict__ scores,
    const float* __restrict__ rois, const int* __restrict__ ph,
    const int* __restrict__ pw, float* __restrict__ out, int R)
{
    __shared__ u64 vkey[RMAX];
    __shared__ float2 p1[RMAX], p2[RMAX];
    __shared__ u64 chunk[64 * 33];
    __shared__ u64 rem[32];
    __shared__ int cnt;

    const int t = threadIdx.x;
    const int lane = t & 63;
    const int c = blockIdx.x + 1;
    const float sh = (float)(*ph), sw = (float)(*pw);

    if (t == 0) cnt = 0;
    if (t < 32) rem[t] = 0;
    __syncthreads();

    for (int r = t; r < R; r += NTH) {
        float p = softmax_p(scores, r, c);
        if (p > SCORE_THRESH) {
            int j = atomicAdd(&cnt, 1);
            vkey[j] = ((u64)(~__float_as_uint(p)) << 32) | (u32)r;
        }
    }
    __syncthreads();
    const int nv = cnt;
    const int nw = (nv + 63) >> 6;

    u64 kk0 = 0, kk1 = 0;
    int r0 = 0, r1 = 0;
    bool in0 = (t < nv), in1 = (t + NTH < nv);
    if (in0) kk0 = vkey[t];
    if (in1) kk1 = vkey[t + NTH];
#pragma unroll 8
    for (int i = 0; i < nv; ++i) {
        u64 k = vkey[i];
        r0 += (k < kk0);
        r1 += (k < kk1);
    }
    __syncthreads();

    for (int u = 0; u < 2; ++u) {
        bool act = u ? in1 : in0;
        if (act) {
            u64 kk = u ? kk1 : kk0;
            int rank = u ? r1 : r0;
            int r = (int)(kk & 0xffffffffu);
            float b0, b1, b2, b3;
            decode_box(rois, loc, r, c, sh, sw, b0, b1, b2, b3);
            vkey[rank] = kk;
            p1[rank] = make_float2(b0, b1);
            p2[rank] = make_float2(b2, b3);
        }
    }
    __syncthreads();

    for (int w = 0; w < nw; ++w) {
        int nwr = nw - w;
        u64 remw = rem[w];
        for (int task = t; task < (nwr << 6); task += NTH) {
            int vr = task >> 6, il = task & 63;
            int i = (w << 6) + il;
            u64 m = 0;
            if (i < nv && !((remw >> il) & 1ull)) {
                int v = w + vr;
                u64 rv = rem[v];
                if (~rv != 0ull) {
                    float2 a1 = p1[i], a2 = p2[i];
                    float iarea = (a2.x - a1.x) * (a2.y - a1.y);
                    int j0 = v << 6;
                    int jhi = min(64, nv - j0);
#pragma unroll 4
                    for (int jj = 0; jj < jhi; ++jj) {
                        float2 b1 = p1[j0 + jj], b2 = p2[j0 + jj];
                        float ty1 = fmaxf(a1.x, b1.x);
                        float tx1 = fmaxf(a1.y, b1.y);
                        float ty2 = fminf(a2.x, b2.x);
                        float tx2 = fminf(a2.y, b2.y);
                        float inter = fmaxf(ty2 - ty1, 0.f) * fmaxf(tx2 - tx1, 0.f);
                        float jarea = (b2.x - b1.x) * (b2.y - b1.y);
                        float uni = fmaxf(iarea + jarea - inter, 1e-10f);
                        if ((double)inter > IOU_MID * (double)uni) m |= 1ull << jj;
                    }
                    if (vr == 0)
                        m &= (il < 63) ? (~0ull << (il + 1)) : 0ull;
                }
            }
            chunk[il * 33 + vr] = m;
        }
        __syncthreads();

        u64 cand = chunk[lane * 33];
        u64 cur = rem[w];
        int remn = nv - (w << 6);
        u64 vb = (remn >= 64) ? ~0ull : ((1ull << remn) - 1ull);
        u64 avail = vb & ~cur;
        u64 kept = 0;
        while (avail) {
            int bb = __ffsll(avail) - 1;
            kept |= 1ull << bb;
            cur |= __shfl(cand, bb, 64);
            avail &= ~(cur | (1ull << bb));
        }
        int vr = t & 31, pg = t >> 5;
        if (vr >= 1 && vr < nwr) {
            u64 acc = 0, km = kept;
            int n = 0;
            while (km) {
                int bb = __ffsll(km) - 1;
                km &= km - 1;
                if ((n & 31) == pg) acc |= chunk[bb * 33 + vr];
                ++n;
            }
            if (acc) atomicOr(&rem[w + vr], acc);
        }
        if (t == 0) rem[w] = cur;
        __syncthreads();
    }

    u16* inv = (u16*)chunk;
    for (int r = t; r < R; r += NTH) inv[r] = 0xffffu;
    __syncthreads();
    for (int i = t; i < nv; i += NTH)
        if (!((rem[i >> 6] >> (i & 63)) & 1ull))
            inv[(int)(vkey[i] & 0xffffffffu)] = (u16)i;
    __syncthreads();
    float* slice = out + (size_t)(c - 1) * R * 5;
    for (int r = t; r < R; r += NTH) {
        int i = inv[r];
        float v0 = 0.f, v1 = 0.f, v2 = 0.f, v3 = 0.f, v4 = 0.f;
        if (i != 0xffff) {
            float2 a1 = p1[i], a2 = p2[i];
            v0 = a1.x; v1 = a1.y; v2 = a2.x; v3 = a2.y;
            v4 = __uint_as_float(~(u32)(vkey[i] >> 32));
        }
        float* p = slice + (size_t)r * 5;
        p[0] = v0; p[1] = v1; p[2] = v2; p[3] = v3; p[4] = v4;
    }
}

extern "C" void kernel_launch(void* const* d_in, const int* in_sizes, int n_in,
                              void* d_out, int out_size, void* d_ws, size_t ws_size,
                              hipStream_t stream) {
    const float* loc    = (const float*)d_in[0];   // (R, 84) f32
    const float* scores = (const float*)d_in[1];   // (R, 21) f32
    const float* rois   = (const float*)d_in[2];   // (R, 4)  f32
    const int*   ph     = (const int*)d_in[3];
    const int*   pw     = (const int*)d_in[4];
    float* out = (float*)d_out;                    // (20, R, 5) f32
    int R = in_sizes[2] / 4;

    // ws: M u64[20][2048*32] (compact) | ord u64[20][2048] | nvv int[32]
    size_t needM   = (size_t)NCO * RCAP * 32 * 8;  // 10.5 MB
    size_t needOrd = (size_t)NCO * RCAP * 8;       // 328 KB
    size_t need    = needM + needOrd + 128;

    if (R <= RCAP && ws_size >= need) {
        char* w   = (char*)d_ws;
        u64* M    = (u64*)w;
        u64* ordp = (u64*)(w + needM);
        int* nvv  = (int*)(w + needM + needOrd);
        sort_kernel<<<NCO, STH, 0, stream>>>(scores, ordp, nvv, R);
        mask_kernel<<<NCO * SUB, TPB, 0, stream>>>(loc, rois, ph, pw, ordp, nvv,
                                                   M, R);
        resolveout_kernel<<<NCO * SUB, TPB, 0, stream>>>(loc, rois, ph, pw,
                                                         ordp, nvv, M, out, R);
    } else if (R <= RMAX) {
        fused_kernel<<<NCO, NTH, 0, stream>>>(loc, scores, rois, ph, pw, out, R);
    }
}